// Round 1
// baseline (623.102 us; speedup 1.0000x reference)
//
#include <hip/hip_runtime.h>

// GraphSage 2-layer forward, MI355X (gfx950).
// Inputs: raw[1e6][128], W1[128][256], W2[128][256] (bf16 OR f32 — detected on
// device), nodes1[40960] i32, neigh1[40960][10] i32, nodes2[4096] i32,
// neigh2[4096][10] i32.  out: h2[4096][128] (dtype follows inputs).
// ws: [0..3] int dtype flag, [256..] h1[40960][128] bf16 (10.5 MB).

typedef __attribute__((ext_vector_type(8))) short  short8;   // 8 bf16 = 16 B
typedef __attribute__((ext_vector_type(8))) __bf16 bf16x8;   // MFMA operand type
typedef __attribute__((ext_vector_type(4))) float  f32x4;

#define K_NEIGH 10
#define NB      32          // nodes per block
#define PITCH   264         // shorts per LDS combined row (256 + 8 pad)

__device__ inline float b2f(short s) {
    union { unsigned int u; float f; } c;
    c.u = ((unsigned int)(unsigned short)s) << 16;
    return c.f;
}
__device__ inline short f2b(float f) {
    union { float f; unsigned int u; } c; c.f = f;
    unsigned int u = c.u;
    return (short)((u + 0x7fffu + ((u >> 16) & 1u)) >> 16);  // RNE
}
__device__ inline bf16x8 as_bf16x8(short8 s) {
    union { short8 s; bf16x8 b; } c; c.s = s; return c.b;
}

// Decide whether float inputs arrived as f32 or bf16. If W1 is f32, the low
// short of each float is mantissa bits: decoded as bf16 its exponent field is
// ~uniform, so P(|x| >= 32) ~ 0.48 per probe. Genuine bf16 weights are
// |w| <= ~0.25 (exponent <= 125). 64 probes: P(misdetect) ~ 5e-19.
__global__ void detect_f32(const unsigned short* __restrict__ w, int* __restrict__ flag) {
    if (threadIdx.x == 0 && blockIdx.x == 0) {
        int f = 0;
        for (int i = 0; i < 64; ++i) {
            unsigned int e = ((unsigned int)w[2 * i] >> 7) & 0xFFu;  // bf16 exp field
            if (e >= 132u) f = 1;                                    // |x| >= 32
        }
        *flag = f;
    }
}

// out[i][o] = relu( sum_j concat(table[nodes[i]], mean_k table[neigh[i][k]])[j] * W[o][j] )
// table_by_flag: table dtype follows *flag (layer 1) or is always bf16 (layer 2 / h1).
// out_by_flag:   out dtype follows *flag (layer 2) or is always bf16 (layer 1 / h1).
// W dtype always follows *flag (W is a harness input in both layers).
__launch_bounds__(256, 2)
__global__ void sage_layer(const void* __restrict__ table,
                           const void* __restrict__ Wv,       // [128][256] row-major
                           const int*  __restrict__ nodes,
                           const int*  __restrict__ neigh,    // [nn][10]
                           void*       __restrict__ outv,     // [nn][128]
                           const int*  __restrict__ flag,
                           const int table_by_flag, const int out_by_flag)
{
    __shared__ __align__(16) short lds[NB * PITCH];
    const int t    = threadIdx.x;
    const int blk  = blockIdx.x;
    const int lane = t & 63;
    const int wave = t >> 6;          // wave w owns out cols [32w, 32w+32)
    const int n15  = lane & 15;
    const int q    = lane >> 4;
    const int f32in = *flag;                       // wave-uniform
    const bool t32 = table_by_flag && f32in;
    const bool o32 = out_by_flag && f32in;

    // ---- B fragments in registers: B[k][n] = W[n][k]; W rows are k-contiguous.
    // Lane layout: n = obase + (lane&15), k = fk*32 + (lane>>4)*8 + i.
    short8 bfrag[2][8];
    if (!f32in) {
        const short* W = (const short*)Wv;
#pragma unroll
        for (int ot = 0; ot < 2; ++ot) {
            const int o = wave * 32 + ot * 16 + n15;
#pragma unroll
            for (int fk = 0; fk < 8; ++fk)
                bfrag[ot][fk] = *(const short8*)(W + o * 256 + fk * 32 + q * 8);
        }
    } else {
        const float* W = (const float*)Wv;
#pragma unroll
        for (int ot = 0; ot < 2; ++ot) {
            const int o = wave * 32 + ot * 16 + n15;
#pragma unroll
            for (int fk = 0; fk < 8; ++fk) {
                const float* p = W + o * 256 + fk * 32 + q * 8;
                f32x4 v0 = *(const f32x4*)p;
                f32x4 v1 = *(const f32x4*)(p + 4);
                short8 s;
#pragma unroll
                for (int i = 0; i < 4; ++i) { s[i] = f2b(v0[i]); s[4 + i] = f2b(v1[i]); }
                bfrag[ot][fk] = s;
            }
        }
    }

    // ---- Stage combined[NB][256] bf16 into LDS: 8 threads/node, 16 dims each.
    {
        const int m    = t >> 3;       // node slot 0..31
        const int part = t & 7;        // dims [part*16, part*16+16)
        const int gi   = blk * NB + m;
        const int self_id = nodes[gi];
        short8 s0, s1;
        float a[16];
#pragma unroll
        for (int i = 0; i < 16; ++i) a[i] = 0.f;

        if (!t32) {
            const short* srow = (const short*)table + (long)self_id * 128 + part * 16;
            s0 = *(const short8*)(srow);
            s1 = *(const short8*)(srow + 8);
            for (int k = 0; k < K_NEIGH; ++k) {
                const int nid = neigh[gi * K_NEIGH + k];
                const short* nrow = (const short*)table + (long)nid * 128 + part * 16;
                short8 v0 = *(const short8*)(nrow);
                short8 v1 = *(const short8*)(nrow + 8);
#pragma unroll
                for (int i = 0; i < 8; ++i) { a[i] += b2f(v0[i]); a[8 + i] += b2f(v1[i]); }
            }
        } else {
            const float* srow = (const float*)table + (long)self_id * 128 + part * 16;
            f32x4 u0 = *(const f32x4*)(srow);
            f32x4 u1 = *(const f32x4*)(srow + 4);
            f32x4 u2 = *(const f32x4*)(srow + 8);
            f32x4 u3 = *(const f32x4*)(srow + 12);
#pragma unroll
            for (int i = 0; i < 4; ++i) {
                s0[i] = f2b(u0[i]); s0[4 + i] = f2b(u1[i]);
                s1[i] = f2b(u2[i]); s1[4 + i] = f2b(u3[i]);
            }
            for (int k = 0; k < K_NEIGH; ++k) {
                const int nid = neigh[gi * K_NEIGH + k];
                const float* nrow = (const float*)table + (long)nid * 128 + part * 16;
                f32x4 v0 = *(const f32x4*)(nrow);
                f32x4 v1 = *(const f32x4*)(nrow + 4);
                f32x4 v2 = *(const f32x4*)(nrow + 8);
                f32x4 v3 = *(const f32x4*)(nrow + 12);
#pragma unroll
                for (int i = 0; i < 4; ++i) {
                    a[i] += v0[i]; a[4 + i] += v1[i]; a[8 + i] += v2[i]; a[12 + i] += v3[i];
                }
            }
        }
        short8 g0, g1;
#pragma unroll
        for (int i = 0; i < 8; ++i) { g0[i] = f2b(a[i] * 0.1f); g1[i] = f2b(a[8 + i] * 0.1f); }
        short* dst = lds + m * PITCH + part * 16;
        *(short8*)(dst)       = s0;   // self -> cols [0,128)
        *(short8*)(dst + 8)   = s1;
        *(short8*)(dst + 128) = g0;   // agg  -> cols [128,256)
        *(short8*)(dst + 136) = g1;
    }
    __syncthreads();

    // ---- MFMA: [32 nodes] x [this wave's 32 outs], K=256.
    f32x4 acc[2][2] = {};
#pragma unroll
    for (int mb = 0; mb < 2; ++mb) {
        // A[m][k]: m = mb*16 + (lane&15), k = fk*32 + (lane>>4)*8 + i
        const short* arow = lds + (mb * 16 + n15) * PITCH + q * 8;
        short8 af[8];
#pragma unroll
        for (int fk = 0; fk < 8; ++fk) af[fk] = *(const short8*)(arow + fk * 32);
#pragma unroll
        for (int ot = 0; ot < 2; ++ot)
#pragma unroll
            for (int fk = 0; fk < 8; ++fk)
                acc[mb][ot] = __builtin_amdgcn_mfma_f32_16x16x32_bf16(
                    as_bf16x8(af[fk]), as_bf16x8(bfrag[ot][fk]), acc[mb][ot], 0, 0, 0);
    }

    // ---- Epilogue: ReLU + store. D layout: col = lane&15, row = (lane>>4)*4 + r.
#pragma unroll
    for (int mb = 0; mb < 2; ++mb)
#pragma unroll
        for (int ot = 0; ot < 2; ++ot) {
            const int col = wave * 32 + ot * 16 + n15;
#pragma unroll
            for (int r = 0; r < 4; ++r) {
                const long row = blk * NB + mb * 16 + q * 4 + r;
                float v = acc[mb][ot][r];
                v = v > 0.f ? v : 0.f;
                if (!o32) ((short*)outv)[row * 128 + col] = f2b(v);
                else      ((float*)outv)[row * 128 + col] = v;
            }
        }
}

extern "C" void kernel_launch(void* const* d_in, const int* in_sizes, int n_in,
                              void* d_out, int out_size, void* d_ws, size_t ws_size,
                              hipStream_t stream) {
    const void* raw    = d_in[0];
    const void* W1     = d_in[1];
    const void* W2     = d_in[2];
    const int*  nodes1 = (const int*)d_in[3];
    const int*  neigh1 = (const int*)d_in[4];
    const int*  nodes2 = (const int*)d_in[5];
    const int*  neigh2 = (const int*)d_in[6];

    int*   flag = (int*)d_ws;
    short* h1   = (short*)((char*)d_ws + 256);    // [B1][128] bf16 = 10.5 MB

    const int B1 = in_sizes[3];                   // 40960
    const int B2 = in_sizes[5];                   // 4096

    detect_f32<<<1, 64, 0, stream>>>((const unsigned short*)W1, flag);
    // Layer 1: gather raw features (dtype per flag) -> h1 bf16 table in ws.
    sage_layer<<<B1 / NB, 256, 0, stream>>>(raw, W1, nodes1, neigh1, h1, flag,
                                            /*table_by_flag=*/1, /*out_by_flag=*/0);
    // Layer 2: gather from bf16 h1 (local indices) -> final output (dtype per flag).
    sage_layer<<<B2 / NB, 256, 0, stream>>>(h1, W2, nodes2, neigh2, d_out, flag,
                                            /*table_by_flag=*/0, /*out_by_flag=*/1);
}